// Round 9
// baseline (69.966 us; speedup 1.0000x reference)
//
#include <hip/hip_runtime.h>

typedef __attribute__((ext_vector_type(8))) short bf16x8;
typedef __attribute__((ext_vector_type(4))) float f32x4;

#define GAMMA_ 0.5f
#define LOG2E_ 1.4426950408889634f

constexpr int D      = 256;   // feature dim (K)
constexpr int BM     = 256;   // rows of X per block
constexpr int BN     = 256;   // X_train cols per j-tile
constexpr int JSPLIT = 8;     // split of M across blockIdx.y

// ---------- helpers ----------
__device__ __forceinline__ unsigned short f2bf(float f) {
    unsigned int x = __float_as_uint(f);
    x += 0x7FFFu + ((x >> 16) & 1u);          // RNE
    return (unsigned short)(x >> 16);
}

__device__ __forceinline__ void gload16(void* lds, const void* g) {
    __builtin_amdgcn_global_load_lds(
        (const __attribute__((address_space(1))) void*)g,
        (__attribute__((address_space(3))) void*)lds, 16, 0, 0);
}

// ---------- prep: cast to bf16, row |x|^2, coefs, out-init ----------
__global__ void prep_all_kernel(const float* __restrict__ X,
                                const float* __restrict__ Xt,
                                const float* __restrict__ alphas,
                                const float* __restrict__ y,
                                const float* __restrict__ b,
                                unsigned short* __restrict__ Abf,
                                unsigned short* __restrict__ Bbf,
                                float* __restrict__ srow,
                                float* __restrict__ tcol,
                                float* __restrict__ coef,
                                float* __restrict__ out,
                                int N, int M) {
    int w = threadIdx.x >> 6;         // one wave per row
    int l = threadIdx.x & 63;
    int row = blockIdx.x * 4 + w;
    if (row >= N + M) return;
    const float* src;
    unsigned short* dst;
    if (row < N) { src = X  + (size_t)row * D;       dst = Abf + (size_t)row * D; }
    else         { src = Xt + (size_t)(row - N) * D; dst = Bbf + (size_t)(row - N) * D; }
    const float4 v = reinterpret_cast<const float4*>(src)[l];
    ushort4 u;
    u.x = f2bf(v.x); u.y = f2bf(v.y); u.z = f2bf(v.z); u.w = f2bf(v.w);
    reinterpret_cast<ushort4*>(dst)[l] = u;
    float ss = v.x * v.x + v.y * v.y + v.z * v.z + v.w * v.w;
    #pragma unroll
    for (int off = 32; off >= 1; off >>= 1) ss += __shfl_xor(ss, off);
    if (l == 0) {
        float folded = -GAMMA_ * LOG2E_ * ss;
        if (row < N) { srow[row] = folded; out[row] = b[0]; }
        else {
            int r2 = row - N;
            tcol[r2] = folded;
            coef[r2] = alphas[r2] * y[r2];
        }
    }
}

// ---------- fused RBF-SVM predict: 256x256 tile, 64-MFMA phases ----------
// pred_i = sum_j exp2( s_i + t_j + (2*g*log2e) * <x_i, xt_j> ) * coef_j + b
// 8 waves (2M x 4N), wave tile 128x64, acc[8][4] in AGPRs.
// Stage stream g = jt*4 + kt: A tile (256x64) + B tile (256x64) staged per
// stage into double-buffered LDS via global_load_lds; counted vmcnt(8);
// 2 barriers and 64 MFMA per wave per stage; epilogue every 4 stages.
__launch_bounds__(512, 2)
__global__ void svm_main_kernel(const unsigned short* __restrict__ Abf,
                                const unsigned short* __restrict__ Bbf,
                                const float* __restrict__ srow,
                                const float* __restrict__ tcol,
                                const float* __restrict__ coef,
                                float* __restrict__ out,
                                int M) {
    __shared__ char L[131072];   // [buf][A 32K | B 32K] x 2

    const int tid = threadIdx.x;
    const int w   = tid >> 6;          // wave 0..7
    const int l   = tid & 63;
    const int wr  = w >> 2;            // 0..1 : row half
    const int wcn = w & 3;             // 0..3 : col quarter
    const int hi  = l >> 4;            // 0..3
    const int lo  = l & 15;
    const int row0   = blockIdx.x * BM;
    const int jspan  = M / JSPLIT;     // 1024
    const int jbase  = blockIdx.y * jspan;
    const int NG     = (jspan / BN) * 4;   // 16 stages

    // per-lane staging invariants: linear LDS dest x, inverse-swizzled src
    int xoff[4], soff[4];
    #pragma unroll
    for (int c = 0; c < 4; ++c) {
        int x   = c * 8192 + tid * 16;
        int row = x >> 7;                        // 128 B per row
        xoff[c] = x;
        soff[c] = row * 512 + ((x & 127) ^ ((row & 7) << 4));
    }
    const char* Abase = (const char*)Abf + (size_t)row0 * 512;
    const char* Bbase = (const char*)Bbf + (size_t)jbase * 512;

    auto issue = [&](int g) {                    // stage g: 8 gload16/thread
        const char* Ag = Abase + (g & 3) * 128;
        const char* Bg = Bbase + (size_t)(g >> 2) * (BN * 512) + (g & 3) * 128;
        char* lb = L + (g & 1) * 32768;
        #pragma unroll
        for (int c = 0; c < 4; ++c) {
            gload16(lb + xoff[c],         Ag + soff[c]);
            gload16(lb + 65536 + xoff[c], Bg + soff[c]);
        }
    };

    f32x4 acc[8][4];
    #pragma unroll
    for (int mi = 0; mi < 8; ++mi)
        #pragma unroll
        for (int ni = 0; ni < 4; ++ni) {
            f32x4 z = {0.f, 0.f, 0.f, 0.f};
            acc[mi][ni] = z;
        }

    const float K2G = 2.0f * GAMMA_ * LOG2E_;

    issue(0);   // prologue: stage 0 in flight

    for (int g = 0; g < NG; ++g) {
        // ---- prefetch next stage; counted wait (never 0 mid-loop) ----
        if (g + 1 < NG) {
            issue(g + 1);
            asm volatile("s_waitcnt vmcnt(8)" ::: "memory");   // stage g done
        } else {
            asm volatile("s_waitcnt vmcnt(0)" ::: "memory");
        }
        __builtin_amdgcn_s_barrier();            // stage-g data visible to all

        const int bufoff = (g & 1) * 32768;
        #pragma unroll
        for (int ks = 0; ks < 2; ++ks) {         // two 32-K slices, no barrier
            bf16x8 af[8], bfr[4];
            #pragma unroll
            for (int mi = 0; mi < 8; ++mi) {
                int row = wr * 128 + mi * 16 + lo;
                int off = bufoff + row * 128
                        + ((ks * 64 + hi * 16) ^ ((row & 7) << 4));
                af[mi] = *(const bf16x8*)(L + off);
            }
            #pragma unroll
            for (int ni = 0; ni < 4; ++ni) {
                int col = wcn * 64 + ni * 16 + lo;
                int off = 65536 + bufoff + col * 128
                        + ((ks * 64 + hi * 16) ^ ((col & 7) << 4));
                bfr[ni] = *(const bf16x8*)(L + off);
            }
            __builtin_amdgcn_s_setprio(1);
            #pragma unroll
            for (int mi = 0; mi < 8; ++mi)
                #pragma unroll
                for (int ni = 0; ni < 4; ++ni)
                    acc[mi][ni] = __builtin_amdgcn_mfma_f32_16x16x32_bf16(
                        af[mi], bfr[ni], acc[mi][ni], 0, 0, 0);
            __builtin_amdgcn_s_setprio(0);
        }
        __builtin_amdgcn_s_barrier();            // all reads of buf done

        // ---- per-j-tile epilogue (next stage's DMA already in flight) ----
        if ((g & 3) == 3) {
            const int jt = g >> 2;
            f32x4 sv[8];
            #pragma unroll
            for (int mi = 0; mi < 8; ++mi)
                sv[mi] = *(const f32x4*)(srow + row0 + wr * 128 + mi * 16 + hi * 4);

            float pac[8][4];
            #pragma unroll
            for (int mi = 0; mi < 8; ++mi)
                #pragma unroll
                for (int r = 0; r < 4; ++r) pac[mi][r] = 0.0f;

            #pragma unroll
            for (int ni = 0; ni < 4; ++ni) {
                int colg = jbase + jt * BN + wcn * 64 + ni * 16 + lo;
                float tv = tcol[colg];
                float cf = coef[colg];
                #pragma unroll
                for (int mi = 0; mi < 8; ++mi) {
                    #pragma unroll
                    for (int r = 0; r < 4; ++r) {
                        float arg = fmaf(acc[mi][ni][r], K2G, sv[mi][r] + tv);
                        float p = __builtin_amdgcn_exp2f(arg);
                        pac[mi][r] = fmaf(p, cf, pac[mi][r]);
                    }
                }
            }
            // reduce across 16 lanes per row, one atomicAdd per row per jt
            #pragma unroll
            for (int mi = 0; mi < 8; ++mi) {
                #pragma unroll
                for (int r = 0; r < 4; ++r) {
                    float v = pac[mi][r];
                    v += __shfl_xor(v, 1);
                    v += __shfl_xor(v, 2);
                    v += __shfl_xor(v, 4);
                    v += __shfl_xor(v, 8);
                    if (lo == 0)
                        atomicAdd(&out[row0 + wr * 128 + mi * 16 + hi * 4 + r], v);
                }
            }
            // reset accumulators for the next j-tile
            #pragma unroll
            for (int mi = 0; mi < 8; ++mi)
                #pragma unroll
                for (int ni = 0; ni < 4; ++ni) {
                    f32x4 z = {0.f, 0.f, 0.f, 0.f};
                    acc[mi][ni] = z;
                }
        }
    }
}

// ---------- launcher ----------
extern "C" void kernel_launch(void* const* d_in, const int* in_sizes, int n_in,
                              void* d_out, int out_size, void* d_ws, size_t ws_size,
                              hipStream_t stream) {
    const float* X      = (const float*)d_in[0];
    const float* Xt     = (const float*)d_in[1];
    const float* alphas = (const float*)d_in[2];
    const float* y      = (const float*)d_in[3];
    const float* b      = (const float*)d_in[4];
    float* out = (float*)d_out;

    const int N = in_sizes[0] / D;   // 8192
    const int M = in_sizes[1] / D;   // 8192

    // workspace: bf16 X | bf16 Xt | srow[N] | tcol[M] | coef[M]
    char* ws = (char*)d_ws;
    unsigned short* Abf = (unsigned short*)ws;
    unsigned short* Bbf = Abf + (size_t)N * D;
    float* srow = (float*)(Bbf + (size_t)M * D);
    float* tcol = srow + N;
    float* coef = tcol + M;

    prep_all_kernel<<<(N + M) / 4, 256, 0, stream>>>(X, Xt, alphas, y, b,
                                                     Abf, Bbf, srow, tcol, coef,
                                                     out, N, M);

    dim3 grid(N / BM, JSPLIT);   // 32 x 8 = 256 blocks = 1 per CU
    svm_main_kernel<<<grid, 512, 0, stream>>>(Abf, Bbf, srow, tcol, coef, out, M);
}